// Round 8
// baseline (498.527 us; speedup 1.0000x reference)
//
#include <hip/hip_runtime.h>

#define T_SEQ 512
#define HID 64
#define MB 16             // batch rows per block
#define NTHREADS 256      // 4 waves, 1/SIMD: each wave 4 L1-tiles + 4 L2-tiles
// OPERAND-FLIPPED MFMA: A = weights (regs), B = h (LDS). D[gate-unit][batch].
// R18 RESTRUCTURE (4 waves x 8 tiles, 1 wave/SIMD):
//   R15-R17 proved MFMA+VALU are the SAME SIMD resource on CDNA4 (3 overlap
//   constructions all neutral; "MFMA issues on the same SIMD units"). The
//   per-SIMD issue sum (~1100cy: 56 trans + 28 MFMA + VALU) is conserved
//   across wave configs; the ~725cy IDLE (LDS read-queue serialization,
//   8-wave barrier convergence, dep bubbles) scales with wave count.
//   4 waves: LDS queue 40->20 b128/step, 4-wave symmetric barrier, ILP=8
//   (8 gate chains + 8 MFMA chains per thread) for compiler bubble-filling.
//   VGPR ~230 fits launch_bounds(256,1) budget of 512.
// R14 lesson: packed-f32 gates serialized the gate chains -> scalar gates.
// R12 lesson: x-in-regs + setprio regressed; cvt_pk + merged-rcp gate = real.
// UNIT PERMUTATION (R15-verified): LDS position p holds unit
//   U(p) = (p&~7)+((p&7)>>1)+((p&1)<<2); thread (wave,quad) owns units
//   wave*16+quad+{0,4,8,12}; h-writes are 2 packed b32 per layer at
//   hp0 = wave*16+2*quad (h_t0,h_t1) and hp1 = hp0+8 (h_t2,h_t3).
// Strides: 104 shorts = 52 dw == 20 mod 32 -> 2-way max read aliasing (benign).
#define A1STR 104
#define A2STR 104

typedef __attribute__((ext_vector_type(8))) short short8;
typedef __attribute__((ext_vector_type(4))) float floatx4;

#define LOG2E 1.4426950408889634f

__device__ __forceinline__ short f2bf_rne(float v) {
  unsigned u = __float_as_uint(v);
  return (short)((u + 0x7FFFu + ((u >> 16) & 1u)) >> 16);
}
__device__ __forceinline__ float rcp_(float x) { return __builtin_amdgcn_rcpf(x); }
__device__ __forceinline__ float exp2_(float x) { return __builtin_amdgcn_exp2f(x); }

// one-instruction RNE pack of two f32 -> 2x bf16 (no builtin on gfx950)
__device__ __forceinline__ unsigned cvt_pk_bf16(float lo, float hi) {
  unsigned r;
  asm("v_cvt_pk_bf16_f32 %0, %1, %2" : "=v"(r) : "v"(lo), "v"(hi));
  return r;
}

// Hot-loop barrier: LDS-publish only (drops the vmcnt(0)/expcnt(0) drain that
// __syncthreads forces; only this-wave x loads are in flight, waited at use).
__device__ __forceinline__ void barrier_lds() {
  asm volatile("s_waitcnt lgkmcnt(0)" ::: "memory");
  __builtin_amdgcn_s_barrier();
  asm volatile("" ::: "memory");
}

// Scalar gates (R3-verified; R14 showed packing the chains hurts latency).
// gates pre-scaled: p[0,1,3] by LOG2E, p[2] by 2*LOG2E. rcp-fused, f-rcp and
// ig-rcp merged (7 trans):
//   t1 = (1+A)(G+1); t2 = (1+F)
//   c  = (c*t1 + (G-1)*t2) * rcp(t1*t2)
//   h  = (C-1) * rcp((1+O)(C+1)),  C = exp2(2*log2e*c)
__device__ __forceinline__ float gate_h(const floatx4 p, float& c) {
  float A = exp2_(-p[0]);
  float F = exp2_(-p[1]);
  float G = exp2_(p[2]);
  float O = exp2_(-p[3]);
  float t1 = (1.f + A) * (G + 1.f);
  float t2 = 1.f + F;
  float num = c * t1 + (G - 1.f) * t2;
  c = num * rcp_(t1 * t2);
  float C = exp2_((2.f * LOG2E) * c);
  return (C - 1.f) * rcp_((1.f + O) * (C + 1.f));
}

// unit stored at LDS h-position p
__device__ __forceinline__ int uofp(int p) {
  return (p & ~7) + ((p & 7) >> 1) + ((p & 1) << 2);
}

// Layer-1 weight at A-frag k-slot (K1=96): k<64 pairs h1 positions, 64..70 x
__device__ __forceinline__ short w1elem(int k, int n, float wsc,
                                        const float* __restrict__ Wih0,
                                        const float* __restrict__ Whh0) {
  float v;
  if      (k < 64) { v = Whh0[n*64 + uofp(k)]; }
  else if (k < 71) { v = Wih0[n*7 + (k - 64)]; }
  else return (short)0;
  return f2bf_rne(v * wsc);
}
// Layer-2 weight (K2=128): k<64 pairs h1 positions, 64..127 pairs h2 positions
__device__ __forceinline__ short w2elem(int k, int n, float wsc,
                                        const float* __restrict__ Wih1,
                                        const float* __restrict__ Whh1) {
  float v;
  if (k < 64) { v = Wih1[n*64 + uofp(k)]; }
  else        { v = Wih1 == Wih1 ? Whh1[n*64 + uofp(k - 64)] : 0; }
  return f2bf_rne(v * wsc);
}

// A = weights (first arg), B = h (second arg)
#define MFMA(A, B, C) __builtin_amdgcn_mfma_f32_16x16x32_bf16((A), (B), (C), 0, 0, 0)

__global__ __launch_bounds__(NTHREADS, 1) void lstm_fused(
    const float* __restrict__ x,
    const float* __restrict__ Wih0, const float* __restrict__ Whh0,
    const float* __restrict__ bih0, const float* __restrict__ bhh0,
    const float* __restrict__ Wih1, const float* __restrict__ Whh1,
    const float* __restrict__ bih1, const float* __restrict__ bhh1,
    const float* __restrict__ Wfc,  const float* __restrict__ bfc,
    float* __restrict__ out)
{
  __shared__ __align__(16) short A1[2][MB][A1STR];
  __shared__ __align__(16) short A2[2][MB][A2STR];
  __shared__ float h2f[MB][HID + 4];

  const int tid  = threadIdx.x;
  const int lane = tid & 63;
  const int wave = tid >> 6;           // 0..3 (all identical roles)
  const int l15  = lane & 15;          // batch column / A-frag row
  const int quad = lane >> 4;
  const int quad8= quad * 8;
  const int g4   = l15 & 3;
  const int b0   = blockIdx.x * MB;
  const int ub   = wave*16 + quad;     // owned units (both layers): +0,4,8,12
  const int hp0  = wave*16 + 2*quad;   // packs (h_t0, h_t1)   [shorts, even]
  const int hp1  = hp0 + 8;            // packs (h_t2, h_t3)
  const float wsc = (g4 == 2) ? 2.f * LOG2E : LOG2E;

  // ---- zero both staging buffers (h(-1) = 0, x pad = 0) ----
  for (int i = tid; i < 2*MB*A1STR/2; i += NTHREADS) ((unsigned*)A1)[i] = 0u;
  for (int i = tid; i < 2*MB*A2STR/2; i += NTHREADS) ((unsigned*)A2)[i] = 0u;
  __syncthreads();   // zeroing fully done before anyone stages x into A1[0]

  // ---- biases for owned units, BOTH layers ----
  floatx4 d0, d1, d2, d3;   // L1 biases (pre-scaled)
  floatx4 e0, e1, e2, e3;   // L2 biases
  #pragma unroll
  for (int g = 0; g < 4; ++g) {
    float ws = (g == 2) ? 2.f * LOG2E : LOG2E;
    d0[g] = (bih0[g*64 + ub     ] + bhh0[g*64 + ub     ]) * ws;
    d1[g] = (bih0[g*64 + ub + 4 ] + bhh0[g*64 + ub + 4 ]) * ws;
    d2[g] = (bih0[g*64 + ub + 8 ] + bhh0[g*64 + ub + 8 ]) * ws;
    d3[g] = (bih0[g*64 + ub + 12] + bhh0[g*64 + ub + 12]) * ws;
    e0[g] = (bih1[g*64 + ub     ] + bhh1[g*64 + ub     ]) * ws;
    e1[g] = (bih1[g*64 + ub + 4 ] + bhh1[g*64 + ub + 4 ]) * ws;
    e2[g] = (bih1[g*64 + ub + 8 ] + bhh1[g*64 + ub + 8 ]) * ws;
    e3[g] = (bih1[g*64 + ub + 12] + bhh1[g*64 + ub + 12]) * ws;
  }

  // ---- x staging: 4 waves x 4 rows each (row = 4*wave + quad).
  // Pair-packed: lane xd2 in 0..3 owns x elements {2*xd2, 2*xd2+1} of its
  // row (element 7 is the zero pad; x[7] never touched -> no OOB). One
  // cvt_pk + one b32 LDS write per lane; prefetch distance = one full step.
  const int xd2  = l15;                // 0..3 active
  const int xrow = 4*wave + quad;
  const bool xact = (xd2 < 4);
  const float* xbase = x + ((size_t)(b0 + xrow) * T_SEQ) * 7 + 2*xd2;
  float xc0 = 0.f, xc1 = 0.f;
  if (xact) {
    *(unsigned*)&A1[0][xrow][64 + 2*xd2] =
        cvt_pk_bf16(xbase[0], (xd2 < 3) ? xbase[1] : 0.f);
    xc0 = xbase[7];
    xc1 = (xd2 < 3) ? xbase[8] : 0.f;
  }

  // ---- weight A-fragments: 4 L1 tiles + 4 L2 tiles per wave ----
  short8 V0[3], V1[3], V2[3], V3[3];   // L1 tiles
  short8 U0[4], U1[4], U2[4], U3[4];   // L2 tiles
#define LOADW1(Wt, t)                                                        \
  { int nt = g4*64 + wave*16 + 4*(t) + (l15 >> 2);                           \
    _Pragma("unroll")                                                        \
    for (int ks = 0; ks < 3; ++ks) { short8 f;                               \
      _Pragma("unroll")                                                      \
      for (int jj = 0; jj < 8; ++jj)                                         \
        f[jj] = w1elem(ks*32 + quad8 + jj, nt, wsc, Wih0, Whh0);             \
      Wt[ks] = f; } }
#define LOADW2(Wt, t)                                                        \
  { int nt = g4*64 + wave*16 + 4*(t) + (l15 >> 2);                           \
    _Pragma("unroll")                                                        \
    for (int ks = 0; ks < 4; ++ks) { short8 f;                               \
      _Pragma("unroll")                                                      \
      for (int jj = 0; jj < 8; ++jj)                                         \
        f[jj] = w2elem(ks*32 + quad8 + jj, nt, wsc, Wih1, Whh1);             \
      Wt[ks] = f; } }
  LOADW1(V0, 0) LOADW1(V1, 1) LOADW1(V2, 2) LOADW1(V3, 3)
  LOADW2(U0, 0) LOADW2(U1, 1) LOADW2(U2, 2) LOADW2(U3, 3)
  __syncthreads();

  // c-state for 8 owned (layer, unit) pairs
  float c10 = 0.f, c11 = 0.f, c12 = 0.f, c13 = 0.f;
  float c20 = 0.f, c21 = 0.f, c22 = 0.f, c23 = 0.f;

#define STEP_X(NXT, XT)                                                      \
    if (xact) {                                                              \
      *(unsigned*)&A1[NXT][xrow][64 + 2*xd2] = cvt_pk_bf16(xc0, xc1);        \
      xc0 = xbase[7 * (XT)];                                                 \
      xc1 = (xd2 < 3) ? xbase[7 * (XT) + 1] : 0.f;                           \
    }

#define L1_MFMAS                                                             \
      floatx4 q0 = MFMA(V0[0], hf0, d0);                                     \
      floatx4 q1 = MFMA(V1[0], hf0, d1);                                     \
      floatx4 q2 = MFMA(V2[0], hf0, d2);                                     \
      floatx4 q3 = MFMA(V3[0], hf0, d3);                                     \
      q0 = MFMA(V0[1], hf1, q0);  q1 = MFMA(V1[1], hf1, q1);                 \
      q2 = MFMA(V2[1], hf1, q2);  q3 = MFMA(V3[1], hf1, q3);                 \
      q0 = MFMA(V0[2], hfx, q0);  q1 = MFMA(V1[2], hfx, q1);                 \
      q2 = MFMA(V2[2], hfx, q2);  q3 = MFMA(V3[2], hfx, q3);

#define L2_MFMAS                                                             \
      floatx4 r0 = MFMA(U0[0], hf0, e0);                                     \
      floatx4 r1 = MFMA(U1[0], hf0, e1);                                     \
      floatx4 r2 = MFMA(U2[0], hf0, e2);                                     \
      floatx4 r3 = MFMA(U3[0], hf0, e3);                                     \
      r0 = MFMA(U0[1], hf1, r0);  r1 = MFMA(U1[1], hf1, r1);                 \
      r2 = MFMA(U2[1], hf1, r2);  r3 = MFMA(U3[1], hf1, r3);                 \
      r0 = MFMA(U0[2], h20, r0);  r1 = MFMA(U1[2], h20, r1);                 \
      r2 = MFMA(U2[2], h20, r2);  r3 = MFMA(U3[2], h20, r3);                 \
      r0 = MFMA(U0[3], h21, r0);  r1 = MFMA(U1[3], h21, r1);                 \
      r2 = MFMA(U2[3], h21, r2);  r3 = MFMA(U3[3], h21, r3);

#define STEP_FULL(CUR, NXT, IT)                                              \
  {                                                                          \
    short8 hf0 = *(const short8*)&A1[CUR][l15][     quad8];                  \
    short8 hf1 = *(const short8*)&A1[CUR][l15][32 + quad8];                  \
    short8 hfx = *(const short8*)&A1[CUR][l15][64 + quad8];                  \
    short8 h20 = *(const short8*)&A2[CUR][l15][     quad8];                  \
    short8 h21 = *(const short8*)&A2[CUR][l15][32 + quad8];                  \
    L1_MFMAS                                                                 \
    L2_MFMAS                                                                 \
    int xt_ = (IT) + 2; if (xt_ > T_SEQ - 1) xt_ = T_SEQ - 1;                \
    STEP_X(NXT, xt_)                                                         \
    float h0 = gate_h(q0, c10);                                              \
    float h1 = gate_h(q1, c11);                                              \
    float h2 = gate_h(q2, c12);                                              \
    float h3 = gate_h(q3, c13);                                              \
    *(unsigned*)&A1[NXT][l15][hp0] = cvt_pk_bf16(h0, h1);                    \
    *(unsigned*)&A1[NXT][l15][hp1] = cvt_pk_bf16(h2, h3);                    \
    float g0 = gate_h(r0, c20);                                              \
    float g1 = gate_h(r1, c21);                                              \
    float g2 = gate_h(r2, c22);                                              \
    float g3 = gate_h(r3, c23);                                              \
    *(unsigned*)&A2[NXT][l15][hp0] = cvt_pk_bf16(g0, g1);                    \
    *(unsigned*)&A2[NXT][l15][hp1] = cvt_pk_bf16(g2, g3);                    \
    barrier_lds();                                                           \
  }

  // ---- it = 0: L1 half only (A2[1] keeps zeros = h2(-1)) ----
  {
    short8 hf0 = *(const short8*)&A1[0][l15][     quad8];
    short8 hf1 = *(const short8*)&A1[0][l15][32 + quad8];
    short8 hfx = *(const short8*)&A1[0][l15][64 + quad8];
    L1_MFMAS
    STEP_X(1, 2)
    float h0 = gate_h(q0, c10);
    float h1 = gate_h(q1, c11);
    float h2 = gate_h(q2, c12);
    float h3 = gate_h(q3, c13);
    *(unsigned*)&A1[1][l15][hp0] = cvt_pk_bf16(h0, h1);
    *(unsigned*)&A1[1][l15][hp1] = cvt_pk_bf16(h2, h3);
    barrier_lds();
  }

  // ---- main: it = 1..510, two steps per trip ----
  #pragma unroll 1
  for (int k = 0; k < 255; ++k) {
    STEP_FULL(1, 0, 2*k + 1)
    STEP_FULL(0, 1, 2*k + 2)
  }
  // ---- it = 511 ----
  STEP_FULL(1, 0, 511)

  // ---- it = 512: L2 half only; write final h2 as f32 (natural unit idx) ----
  {
    short8 hf0 = *(const short8*)&A1[0][l15][     quad8];
    short8 hf1 = *(const short8*)&A1[0][l15][32 + quad8];
    short8 h20 = *(const short8*)&A2[0][l15][     quad8];
    short8 h21 = *(const short8*)&A2[0][l15][32 + quad8];
    L2_MFMAS
    h2f[l15][ub     ] = gate_h(r0, c20);
    h2f[l15][ub + 4 ] = gate_h(r1, c21);
    h2f[l15][ub + 8 ] = gate_h(r2, c22);
    h2f[l15][ub + 12] = gate_h(r3, c23);
    __syncthreads();
  }

  // ---- final FC ----
  if (tid < MB * 4) {
    int bbf = tid >> 2, o = tid & 3;
    float acc = bfc[o];
    #pragma unroll 8
    for (int kk = 0; kk < HID; ++kk) acc += h2f[bbf][kk] * Wfc[o*HID + kk];
    out[(size_t)(b0 + bbf) * 4 + o] = acc;
  }
}

extern "C" void kernel_launch(void* const* d_in, const int* in_sizes, int n_in,
                              void* d_out, int out_size, void* d_ws, size_t ws_size,
                              hipStream_t stream) {
  const float* x    = (const float*)d_in[0];
  const float* Wih0 = (const float*)d_in[1];
  const float* Whh0 = (const float*)d_in[2];
  const float* bih0 = (const float*)d_in[3];
  const float* bhh0 = (const float*)d_in[4];
  const float* Wih1 = (const float*)d_in[5];
  const float* Whh1 = (const float*)d_in[6];
  const float* bih1 = (const float*)d_in[7];
  const float* bhh1 = (const float*)d_in[8];
  const float* Wfc  = (const float*)d_in[9];
  const float* bfc  = (const float*)d_in[10];
  (void)d_ws; (void)ws_size; (void)n_in; (void)out_size;

  const int B = in_sizes[0] / (T_SEQ * 7);   // 4096
  dim3 grid(B / MB);
  lstm_fused<<<grid, NTHREADS, 0, stream>>>(x, Wih0, Whh0, bih0, bhh0,
                                            Wih1, Whh1, bih1, bhh1, Wfc, bfc,
                                            (float*)d_out);
}

// Round 10
// 435.964 us; speedup vs baseline: 1.1435x; 1.1435x over previous
//
#include <hip/hip_runtime.h>

#define T_SEQ 512
#define HID 64
#define MB 16             // batch rows per block
#define NTHREADS 512      // 8 waves: 0-3 layer1 (4 tiles each), 4-7 layer2 (4 tiles)
// OPERAND-FLIPPED MFMA: A = weights (regs), B = h (LDS). D[gate-unit][batch].
// R20 = R15 (best measured: 390us) + CONSECUTIVE-UNIT PERMUTATION so the
//   4 owned h values store as ONE plain ds_write_b64 (R19's ds_write2 asm
//   failed: DS vaddr is 32-bit, generic pointer operand emitted a VGPR pair).
// Structure-space results (all measured):
//   16w x 2t = 398 | 8w x 4t = 390 (BEST) | 8w merged-layer = 397-403 |
//   4w x 8t = 455 (1 wave/SIMD exposes latency; co-wave fills ~400cy of
//   bubbles - R18's VALUBusy DROPPED while wall rose 16%).
// Overlap attempts (R16 chain-pair, R17 merged+sched_barrier) neutral:
//   MFMA and VALU are the same per-SIMD issue resource on CDNA4; per-SIMD
//   issue work (~448cy trans + ~543 MFMA + ~300 gate VALU + ~110 misc) is
//   conserved across schedules. Residual ~425cy/step = barrier convergence +
//   post-barrier ds_read latency + dep tails of the 513-step serial
//   recurrence (all-to-all h exchange per step is algorithmically required).
// R14 lesson: packed-f32 gates serialized the gate chains -> scalar gates.
// R12 lesson: x-in-regs + setprio regressed; cvt_pk + merged-rcp gate = real.
// UNIT PERMUTATION (R20): LDS position p holds unit
//   U(p) = (p&~15) + ((p>>2)&3) + ((p&3)<<2)   [(quad,tile) swap, bijective]
// -> thread (w0,quad) owns units w0*16+quad+{0,4,8,12} at positions
//    w0*16+4*quad+{0,1,2,3}: one 8B-aligned ds_write_b64.
// Strides: 104 shorts = 52 dw == 20 mod 32 -> 2-way max aliasing (benign).
#define A1STR 104
#define A2STR 104

typedef __attribute__((ext_vector_type(8))) short short8;
typedef __attribute__((ext_vector_type(4))) float floatx4;
typedef __attribute__((ext_vector_type(2))) unsigned uint2v;

#define LOG2E 1.4426950408889634f

__device__ __forceinline__ short f2bf_rne(float v) {
  unsigned u = __float_as_uint(v);
  return (short)((u + 0x7FFFu + ((u >> 16) & 1u)) >> 16);
}
__device__ __forceinline__ float rcp_(float x) { return __builtin_amdgcn_rcpf(x); }
__device__ __forceinline__ float exp2_(float x) { return __builtin_amdgcn_exp2f(x); }

// one-instruction RNE pack of two f32 -> 2x bf16 (no builtin on gfx950)
__device__ __forceinline__ unsigned cvt_pk_bf16(float lo, float hi) {
  unsigned r;
  asm("v_cvt_pk_bf16_f32 %0, %1, %2" : "=v"(r) : "v"(lo), "v"(hi));
  return r;
}

// Hot-loop barrier: LDS-publish only (drops the vmcnt(0)/expcnt(0) drain that
// __syncthreads forces; only this-wave x loads are in flight, waited at use).
__device__ __forceinline__ void barrier_lds() {
  asm volatile("s_waitcnt lgkmcnt(0)" ::: "memory");
  __builtin_amdgcn_s_barrier();
  asm volatile("" ::: "memory");
}

// Scalar gates (R3-verified; R14 showed packing the chains hurts latency).
// gates pre-scaled: p[0,1,3] by LOG2E, p[2] by 2*LOG2E. rcp-fused, f-rcp and
// ig-rcp merged (7 trans):
//   t1 = (1+A)(G+1); t2 = (1+F)
//   c  = (c*t1 + (G-1)*t2) * rcp(t1*t2)
//   h  = (C-1) * rcp((1+O)(C+1)),  C = exp2(2*log2e*c)
__device__ __forceinline__ float gate_h(const floatx4 p, float& c) {
  float A = exp2_(-p[0]);
  float F = exp2_(-p[1]);
  float G = exp2_(p[2]);
  float O = exp2_(-p[3]);
  float t1 = (1.f + A) * (G + 1.f);
  float t2 = 1.f + F;
  float num = c * t1 + (G - 1.f) * t2;
  c = num * rcp_(t1 * t2);
  float C = exp2_((2.f * LOG2E) * c);
  return (C - 1.f) * rcp_((1.f + O) * (C + 1.f));
}

// unit stored at LDS h-position p: (quad,tile) swap within each 16-block
__device__ __forceinline__ int uofp(int p) {
  return (p & ~15) + ((p >> 2) & 3) + ((p & 3) << 2);
}

// Layer-1 weight at A-frag k-slot (K1=96): k<64 pairs h1 positions, 64..70 x
__device__ __forceinline__ short w1elem(int k, int n, float wsc,
                                        const float* __restrict__ Wih0,
                                        const float* __restrict__ Whh0) {
  float v;
  if      (k < 64) { v = Whh0[n*64 + uofp(k)]; }
  else if (k < 71) { v = Wih0[n*7 + (k - 64)]; }
  else return (short)0;
  return f2bf_rne(v * wsc);
}
// Layer-2 weight (K2=128): k<64 pairs h1 positions, 64..127 pairs h2 positions
__device__ __forceinline__ short w2elem(int k, int n, float wsc,
                                        const float* __restrict__ Wih1,
                                        const float* __restrict__ Whh1) {
  float v;
  if (k < 64) { v = Wih1[n*64 + uofp(k)]; }
  else        { v = Whh1[n*64 + uofp(k - 64)]; }
  return f2bf_rne(v * wsc);
}

// A = weights (first arg), B = h (second arg)
#define MFMA(A, B, C) __builtin_amdgcn_mfma_f32_16x16x32_bf16((A), (B), (C), 0, 0, 0)

__global__ __launch_bounds__(NTHREADS, 2) void lstm_fused(
    const float* __restrict__ x,
    const float* __restrict__ Wih0, const float* __restrict__ Whh0,
    const float* __restrict__ bih0, const float* __restrict__ bhh0,
    const float* __restrict__ Wih1, const float* __restrict__ Whh1,
    const float* __restrict__ bih1, const float* __restrict__ bhh1,
    const float* __restrict__ Wfc,  const float* __restrict__ bfc,
    float* __restrict__ out)
{
  __shared__ __align__(16) short A1[2][MB][A1STR];
  __shared__ __align__(16) short A2[2][MB][A2STR];
  __shared__ float h2f[MB][HID + 4];

  const int tid  = threadIdx.x;
  const int lane = tid & 63;
  const int wave = tid >> 6;           // 0..7
  const int w0   = wave & 3;           // index within layer group
  const bool isL1 = wave < 4;
  const int l15  = lane & 15;          // batch column (output) / A-frag row
  const int quad = lane >> 4;
  const int quad8= quad * 8;
  const int g4   = l15 & 3;
  const int b0   = blockIdx.x * MB;
  const int ub   = w0*16 + quad;       // owned units: ub, ub+4, ub+8, ub+12
  const int wpos = w0*16 + 4*quad;     // 4 consecutive shorts (8B aligned)
  const float wsc = (g4 == 2) ? 2.f * LOG2E : LOG2E;

  // ---- zero both staging buffers (h(-1) = 0, x pad = 0) ----
  for (int i = tid; i < 2*MB*A1STR/2; i += NTHREADS) ((unsigned*)A1)[i] = 0u;
  for (int i = tid; i < 2*MB*A2STR/2; i += NTHREADS) ((unsigned*)A2)[i] = 0u;
  __syncthreads();   // zeroing fully done before anyone stages x into A1[0]

  // ---- biases for owned units (this thread's layer) ----
  const float* bi_ = isL1 ? bih0 : bih1;
  const float* bh_ = isL1 ? bhh0 : bhh1;
  floatx4 bs0, bs1, bs2, bs3;
  #pragma unroll
  for (int g = 0; g < 4; ++g) {
    float ws = (g == 2) ? 2.f * LOG2E : LOG2E;
    bs0[g] = (bi_[g*64 + ub     ] + bh_[g*64 + ub     ]) * ws;
    bs1[g] = (bi_[g*64 + ub + 4 ] + bh_[g*64 + ub + 4 ]) * ws;
    bs2[g] = (bi_[g*64 + ub + 8 ] + bh_[g*64 + ub + 8 ]) * ws;
    bs3[g] = (bi_[g*64 + ub + 12] + bh_[g*64 + ub + 12]) * ws;
  }

  // ---- x staging: 4 L1 waves x 4 rows each (row = 4*w0 + quad).
  // Pair-packed: lane xd2 in 0..3 owns x elements {2*xd2, 2*xd2+1} of its
  // row (element 7 is the zero pad; x[7] never touched -> no OOB). One
  // cvt_pk + one b32 LDS write per lane; prefetch distance = one full step.
  const int xd2  = l15;                // 0..3 active
  const int xrow = 4*w0 + quad;
  const bool xact = isL1 && (xd2 < 4);
  const float* xbase = x + ((size_t)(b0 + xrow) * T_SEQ) * 7 + 2*xd2;
  float xc0 = 0.f, xc1 = 0.f;
  if (xact) {
    *(unsigned*)&A1[0][xrow][64 + 2*xd2] =
        cvt_pk_bf16(xbase[0], (xd2 < 3) ? xbase[1] : 0.f);
    xc0 = xbase[7];
    xc1 = (xd2 < 3) ? xbase[8] : 0.f;
  }

  // ---- weight A-fragments: 4 tiles per wave ----
  short8 W0[4], W1[4], W2[4], W3[4];
#define LOADW1(Wt, t)                                                        \
  { int nt = g4*64 + w0*16 + 4*(t) + (l15 >> 2);                             \
    _Pragma("unroll")                                                        \
    for (int ks = 0; ks < 3; ++ks) { short8 f;                               \
      _Pragma("unroll")                                                      \
      for (int jj = 0; jj < 8; ++jj)                                         \
        f[jj] = w1elem(ks*32 + quad8 + jj, nt, wsc, Wih0, Whh0);             \
      Wt[ks] = f; } }
#define LOADW2(Wt, t)                                                        \
  { int nt = g4*64 + w0*16 + 4*(t) + (l15 >> 2);                             \
    _Pragma("unroll")                                                        \
    for (int ks = 0; ks < 4; ++ks) { short8 f;                               \
      _Pragma("unroll")                                                      \
      for (int jj = 0; jj < 8; ++jj)                                         \
        f[jj] = w2elem(ks*32 + quad8 + jj, nt, wsc, Wih1, Whh1);             \
      Wt[ks] = f; } }
  if (isL1) {
    LOADW1(W0, 0) LOADW1(W1, 1) LOADW1(W2, 2) LOADW1(W3, 3)
  } else {
    LOADW2(W0, 0) LOADW2(W1, 1) LOADW2(W2, 2) LOADW2(W3, 3)
  }
  __syncthreads();

  float c0 = 0.f, c1 = 0.f, c2 = 0.f, c3 = 0.f;   // c-state, 4 owned units

#define STEP_X(NXT, XT)                                                      \
    if (xact) {                                                              \
      *(unsigned*)&A1[NXT][xrow][64 + 2*xd2] = cvt_pk_bf16(xc0, xc1);        \
      xc0 = xbase[7 * (XT)];                                                 \
      xc1 = (xd2 < 3) ? xbase[7 * (XT) + 1] : 0.f;                           \
    }

// Round-robin MFMA issue across the 4 independent tile chains.
#define L1_MFMAS                                                             \
      floatx4 p0 = MFMA(W0[0], hf0, bs0);                                    \
      floatx4 p1 = MFMA(W1[0], hf0, bs1);                                    \
      floatx4 p2 = MFMA(W2[0], hf0, bs2);                                    \
      floatx4 p3 = MFMA(W3[0], hf0, bs3);                                    \
      p0 = MFMA(W0[1], hf1, p0);  p1 = MFMA(W1[1], hf1, p1);                 \
      p2 = MFMA(W2[1], hf1, p2);  p3 = MFMA(W3[1], hf1, p3);                 \
      p0 = MFMA(W0[2], hfx, p0);  p1 = MFMA(W1[2], hfx, p1);                 \
      p2 = MFMA(W2[2], hfx, p2);  p3 = MFMA(W3[2], hfx, p3);

#define L2_MFMAS                                                             \
      floatx4 p0 = MFMA(W0[0], hf0, bs0);                                    \
      floatx4 p1 = MFMA(W1[0], hf0, bs1);                                    \
      floatx4 p2 = MFMA(W2[0], hf0, bs2);                                    \
      floatx4 p3 = MFMA(W3[0], hf0, bs3);                                    \
      p0 = MFMA(W0[1], hf1, p0);  p1 = MFMA(W1[1], hf1, p1);                 \
      p2 = MFMA(W2[1], hf1, p2);  p3 = MFMA(W3[1], hf1, p3);                 \
      p0 = MFMA(W0[2], h20, p0);  p1 = MFMA(W1[2], h20, p1);                 \
      p2 = MFMA(W2[2], h20, p2);  p3 = MFMA(W3[2], h20, p3);                 \
      p0 = MFMA(W0[3], h21, p0);  p1 = MFMA(W1[3], h21, p1);                 \
      p2 = MFMA(W2[3], h21, p2);  p3 = MFMA(W3[3], h21, p3);

#define GATES_AND_WRITE(DST)                                                 \
      float h0 = gate_h(p0, c0);                                             \
      float h1 = gate_h(p1, c1);                                             \
      float h2 = gate_h(p2, c2);                                             \
      float h3 = gate_h(p3, c3);                                             \
      uint2v hv_;                                                            \
      hv_.x = cvt_pk_bf16(h0, h1);                                           \
      hv_.y = cvt_pk_bf16(h2, h3);                                           \
      *(uint2v*)&DST[l15][wpos] = hv_;

#define STEP_FULL(CUR, NXT, IT)                                              \
  {                                                                          \
    if (isL1) {                                                              \
      int xt_ = (IT) + 2; if (xt_ > T_SEQ - 1) xt_ = T_SEQ - 1;              \
      STEP_X(NXT, xt_)                                                       \
      short8 hf0 = *(const short8*)&A1[CUR][l15][     quad8];                \
      short8 hf1 = *(const short8*)&A1[CUR][l15][32 + quad8];                \
      short8 hfx = *(const short8*)&A1[CUR][l15][64 + quad8];                \
      L1_MFMAS                                                               \
      GATES_AND_WRITE(A1[NXT])                                               \
    } else {                                                                 \
      short8 hf0 = *(const short8*)&A1[CUR][l15][     quad8];                \
      short8 hf1 = *(const short8*)&A1[CUR][l15][32 + quad8];                \
      short8 h20 = *(const short8*)&A2[CUR][l15][     quad8];                \
      short8 h21 = *(const short8*)&A2[CUR][l15][32 + quad8];                \
      L2_MFMAS                                                               \
      GATES_AND_WRITE(A2[NXT])                                               \
    }                                                                        \
    barrier_lds();                                                           \
  }

  // ---- it = 0: L1 only (A2[1] keeps zeros = h2(-1)) ----
  {
    if (isL1) {
      STEP_X(1, 2)
      short8 hf0 = *(const short8*)&A1[0][l15][     quad8];
      short8 hf1 = *(const short8*)&A1[0][l15][32 + quad8];
      short8 hfx = *(const short8*)&A1[0][l15][64 + quad8];
      L1_MFMAS
      GATES_AND_WRITE(A1[1])
    }
    barrier_lds();
  }

  // ---- main: it = 1..510, two steps per trip ----
  #pragma unroll 1
  for (int k = 0; k < 255; ++k) {
    STEP_FULL(1, 0, 2*k + 1)
    STEP_FULL(0, 1, 2*k + 2)
  }
  // ---- it = 511 ----
  STEP_FULL(1, 0, 511)

  // ---- it = 512: L2 only; write final h2 as f32 (natural unit index) ----
  {
    if (!isL1) {
      short8 hf0 = *(const short8*)&A1[0][l15][     quad8];
      short8 hf1 = *(const short8*)&A1[0][l15][32 + quad8];
      short8 h20 = *(const short8*)&A2[0][l15][     quad8];
      short8 h21 = *(const short8*)&A2[0][l15][32 + quad8];
      L2_MFMAS
      h2f[l15][ub     ] = gate_h(p0, c0);
      h2f[l15][ub + 4 ] = gate_h(p1, c1);
      h2f[l15][ub + 8 ] = gate_h(p2, c2);
      h2f[l15][ub + 12] = gate_h(p3, c3);
    }
    __syncthreads();
  }

  // ---- final FC ----
  if (tid < MB * 4) {
    int bbf = tid >> 2, o = tid & 3;
    float acc = bfc[o];
    #pragma unroll 8
    for (int kk = 0; kk < HID; ++kk) acc += h2f[bbf][kk] * Wfc[o*HID + kk];
    out[(size_t)(b0 + bbf) * 4 + o] = acc;
  }
}

extern "C" void kernel_launch(void* const* d_in, const int* in_sizes, int n_in,
                              void* d_out, int out_size, void* d_ws, size_t ws_size,
                              hipStream_t stream) {
  const float* x    = (const float*)d_in[0];
  const float* Wih0 = (const float*)d_in[1];
  const float* Whh0 = (const float*)d_in[2];
  const float* bih0 = (const float*)d_in[3];
  const float* bhh0 = (const float*)d_in[4];
  const float* Wih1 = (const float*)d_in[5];
  const float* Whh1 = (const float*)d_in[6];
  const float* bih1 = (const float*)d_in[7];
  const float* bhh1 = (const float*)d_in[8];
  const float* Wfc  = (const float*)d_in[9];
  const float* bfc  = (const float*)d_in[10];
  (void)d_ws; (void)ws_size; (void)n_in; (void)out_size;

  const int B = in_sizes[0] / (T_SEQ * 7);   // 4096
  dim3 grid(B / MB);
  lstm_fused<<<grid, NTHREADS, 0, stream>>>(x, Wih0, Whh0, bih0, bhh0,
                                            Wih1, Whh1, bih1, bhh1, Wfc, bfc,
                                            (float*)d_out);
}